// Round 4
// baseline (204.037 us; speedup 1.0000x reference)
//
#include <hip/hip_runtime.h>
#include <math.h>

// Problem constants (fixed by reference: enc (32,64,64,64) fp32, embed (512,64) fp32)
#define DQ 64
#define KQ 512
#define NVEC 131072
#define QOUT_SIZE (NVEC * DQ)              // 8388608
#define LOSS_OFF QOUT_SIZE
#define IDX_OFF (QOUT_SIZE + 1)

#define RPW 32                             // rows per wave (2 MFMA A-tiles)
#define WPB 2                              // waves per block (128 threads)
#define VPB (RPW * WPB)                    // 64 rows per block
#define NBLK (NVEC / VPB)                  // 2048 blocks -> exactly 8 per CU
// Packed-key scheme: esq stored as |e|^2 + 256 so v = esq - 2*dot > 0 always
// (x_sq ~ chi2(64); 256 is 17 sigma -> impossible). Low 9 mantissa bits carry
// the code index (<=511 ulp ~ 0.002 at d2~60). TIE_THR = fp16-product 5.5
// sigma + pack noise.
#define ESQ_OFF 256.0f
#define TIE_THR 0.09f

typedef __attribute__((ext_vector_type(8))) _Float16 half8;        // 8 f16 = 1 MFMA A/B frag
typedef __attribute__((ext_vector_type(4))) float f32x4;           // MFMA C/D frag

static __device__ __forceinline__ void cvt8h(float4 a, float4 b, half8& h) {
    // RNE f32->f16 (v_cvt_f16_f32 default mode).
    h[0] = (_Float16)a.x; h[1] = (_Float16)a.y; h[2] = (_Float16)a.z; h[3] = (_Float16)a.w;
    h[4] = (_Float16)b.x; h[5] = (_Float16)b.y; h[6] = (_Float16)b.z; h[7] = (_Float16)b.w;
}

// key = distance value with low 9 mantissa bits replaced by the code index.
// Values strictly positive -> IEEE float ordering == bit ordering.
static __device__ __forceinline__ float packk(float v, int code) {
    return __uint_as_float((__float_as_uint(v) & 0xFFFFFE00u) | (unsigned)code);
}

// Init: fp16 codebook, PLAIN row-major layout (no swizzle: main kernel reads
// it from global/L1, no LDS banks involved). esq = |e|^2 + 256 (see above).
__global__ void vq_init_kernel(const float* __restrict__ embed,
                               unsigned short* __restrict__ eh,
                               float* __restrict__ esq,
                               float* __restrict__ out) {
    const int t = blockIdx.x * 64 + threadIdx.x;   // 0..4095
    if (t == 0) out[LOSS_OFF] = 0.0f;
    const int k = t >> 3;            // codebook row
    const int c = t & 7;             // 16-byte chunk (8 dims)
    const float4* p = (const float4*)(embed + (size_t)k * DQ + c * 8);
    float4 a = p[0], b = p[1];
    half8 h;
    cvt8h(a, b, h);
    *(half8*)(eh + (size_t)k * DQ + c * 8) = h;

    float ps = 0.f;
    ps = fmaf(a.x, a.x, ps); ps = fmaf(a.y, a.y, ps); ps = fmaf(a.z, a.z, ps); ps = fmaf(a.w, a.w, ps);
    ps = fmaf(b.x, b.x, ps); ps = fmaf(b.y, b.y, ps); ps = fmaf(b.z, b.z, ps); ps = fmaf(b.w, b.w, ps);
    ps += __shfl_xor(ps, 1);
    ps += __shfl_xor(ps, 2);
    ps += __shfl_xor(ps, 4);
    if (c == 0) esq[k] = ps + ESQ_OFF;
}

// R16 == R15 resubmitted (R15 failed on container infra, not kernel).
// Post-mortem R13/R14: per-wave latency is ~5-7 us in ALL structures and
// per-WG latency = waves/WG x per-wave -> co-resident waves never overlap
// (correlated stalls, ~1 effective wave/SIMD). Fix = independence, not
// barriers: (1) NO LDS codebook — B-frags straight from global (64 KB, L1/L2
// resident; total 268 MB ~ 8 us at L2 BW); no barrier, no staging, no
// inter-wave coupling. (2) 2-wave WGs, grid 2048 = 8 WGs/CU; 18 KB LDS pad
// pins provable residency at 8 WGs/CU -> VGPR budget 512/4 = 128 (R12 rule),
// demand ~105 -> no spill, 16 independent waves/CU. (3) fully-unrolled
// k-loop with X/Y ping-pong so next pair's loads fly under current MFMA+VALU.
// R3 lesson kept: VGPR arrays only indexed by fully-unrolled constants.
__global__ __launch_bounds__(128) void vq_mfma_kernel(const float* __restrict__ enc,
                                                      const float* __restrict__ embed,
                                                      const unsigned short* __restrict__ eh,
                                                      const float* __restrict__ esq,
                                                      float* __restrict__ out) {
    __shared__ int bidx_s[VPB];                // 256 B
    __shared__ int flag_s[VPB];                // 256 B
    __shared__ float red[WPB];
    __shared__ float pad[4608];                // 18 KB occupancy shaper (see above)

    const int tid = threadIdx.x;               // 0..127
    const int lane = tid & 63;
    const int w = tid >> 6;                    // wave 0..1
    const int l15 = lane & 15;
    const int l4 = lane >> 4;                  // 0..3
    const int vb = blockIdx.x * VPB + w * RPW;

    // Keep the pad live: the guard depends on runtime data the compiler
    // cannot constant-fold (enc contents), and is never true for real input
    // magnitudes... actually use vb bound: grid is runtime-sized, so vb can
    // in principle reach INT_MAX from the compiler's view.
    if (vb > 0x7ffffff0) pad[tid] = 0.f;

    // A fragments for 2 tiles: row m = l15 (+a*16), k-chunks l4*8 and 32+l4*8.
    half8 ahA[2], ahB[2];
#pragma unroll
    for (int a = 0; a < 2; a++) {
        const float* base = enc + (size_t)(vb + a * 16 + l15) * DQ + l4 * 8;
        const float4* p0 = (const float4*)base;
        const float4* p1 = (const float4*)(base + 32);
        cvt8h(p0[0], p0[1], ahA[a]);
        cvt8h(p1[0], p1[1], ahB[a]);
    }

    float m1[8], m2[8];
#pragma unroll
    for (int r = 0; r < 8; r++) { m1[r] = 3.0e38f; m2[r] = 3.0e38f; }

    // B-frag base for this lane: code row (b*16 + l15), dims l4*8 (+32).
    const unsigned short* ebase = eh + (size_t)l15 * DQ + l4 * 8;

    // LDP: load pair P (codes P*32..P*32+31): 4 x global_load_dwordx4 (L1/L2
    // hot) + 2 esq dwords. Ping-pong X/Y so loads overlap compute.
#define LDP(B0, B1, B2, B3, E0, E1, P) { \
    const unsigned short* _p = ebase + (size_t)(P) * 32 * DQ; \
    B0 = *(const half8*)(_p);            B1 = *(const half8*)(_p + 32); \
    B2 = *(const half8*)(_p + 16 * DQ);  B3 = *(const half8*)(_p + 16 * DQ + 32); \
    E0 = esq[(P) * 32 + l15];            E1 = esq[(P) * 32 + 16 + l15]; }

#define BODY(P, B0, B1, B2, B3, E0, E1) { \
    const int c0 = (P) * 32 + l15; \
    _Pragma("unroll") \
    for (int a = 0; a < 2; a++) { \
        f32x4 acc0 = {0.f, 0.f, 0.f, 0.f}; \
        f32x4 acc1 = {0.f, 0.f, 0.f, 0.f}; \
        acc0 = __builtin_amdgcn_mfma_f32_16x16x32_f16(ahA[a], B0, acc0, 0, 0, 0); \
        acc0 = __builtin_amdgcn_mfma_f32_16x16x32_f16(ahB[a], B1, acc0, 0, 0, 0); \
        acc1 = __builtin_amdgcn_mfma_f32_16x16x32_f16(ahA[a], B2, acc1, 0, 0, 0); \
        acc1 = __builtin_amdgcn_mfma_f32_16x16x32_f16(ahB[a], B3, acc1, 0, 0, 0); \
        _Pragma("unroll") \
        for (int r = 0; r < 4; r++) { \
            const int i = a * 4 + r; \
            const float k0 = packk(fmaf(-2.0f, acc0[r], E0), c0); \
            const float k1 = packk(fmaf(-2.0f, acc1[r], E1), c0 + 16); \
            const float mo = m1[i]; \
            m1[i] = fminf(fminf(mo, k0), k1); \
            m2[i] = fminf(m2[i], __builtin_amdgcn_fmed3f(mo, k0, k1)); \
        } \
    } }

    half8 X0, X1, X2, X3, Y0, Y1, Y2, Y3;
    float xe0, xe1, ye0, ye1;
    LDP(X0, X1, X2, X3, xe0, xe1, 0)
#pragma unroll
    for (int p = 0; p < 16; p += 2) {
        LDP(Y0, Y1, Y2, Y3, ye0, ye1, p + 1)
        BODY(p, X0, X1, X2, X3, xe0, xe1)
        if (p + 2 < 16) LDP(X0, X1, X2, X3, xe0, xe1, p + 2)
        BODY(p + 1, Y0, Y1, Y2, Y3, ye0, ye1)
    }
#undef LDP
#undef BODY

    // Cross-lane merge over the 16 cols (xor on lane&15 bits). Keys carry the
    // code index -> only 2 shuffles per r.
#pragma unroll
    for (int m = 1; m <= 8; m <<= 1) {
#pragma unroll
        for (int r = 0; r < 8; r++) {
            const float o1 = __shfl_xor(m1[r], m);
            const float o2 = __shfl_xor(m2[r], m);
            m2[r] = fminf(fminf(m2[r], o2), fmaxf(m1[r], o1));
            m1[r] = fminf(m1[r], o1);
        }
    }

    if (l15 == 0) {
#pragma unroll
        for (int a = 0; a < 2; a++)
#pragma unroll
            for (int r = 0; r < 4; r++) {
                const int row = a * 16 + l4 * 4 + r;
                bidx_s[w * RPW + row] = (int)(__float_as_uint(m1[a * 4 + r]) & 511u);
                flag_s[w * RPW + row] = (m2[a * 4 + r] - m1[a * 4 + r] < TIE_THR) ? 1 : 0;
            }
    }
    // bidx_s/flag_s are per-wave segments -> wave-internal visibility only.

    // Exact fp64 rescan of flagged rows (wave-uniform branch; ~1.3% of rows).
    for (int row = 0; row < RPW; row++) {
        if (flag_s[w * RPW + row]) {
            const int v = vb + row;
            const float4* xe = (const float4*)(enc + (size_t)v * DQ);
            unsigned long long best = ~0ULL;
            for (int q = 0; q < 8; q++) {
                const int c = lane * 8 + q;
                const float4* ee = (const float4*)(embed + (size_t)c * DQ);
                double a = 0.0;
                for (int j = 0; j < 16; j++) {          // global ptrs: runtime j fine
                    float4 xx = xe[j], ez = ee[j];
                    double d0 = (double)xx.x - (double)ez.x; a = fma(d0, d0, a);
                    double d1 = (double)xx.y - (double)ez.y; a = fma(d1, d1, a);
                    double d2 = (double)xx.z - (double)ez.z; a = fma(d2, d2, a);
                    double d3 = (double)xx.w - (double)ez.w; a = fma(d3, d3, a);
                }
                unsigned long long pk =
                    (((unsigned long long)__double_as_longlong(a)) & ~511ULL) | (unsigned)c;
                best = (pk < best) ? pk : best;
            }
#pragma unroll
            for (int mm = 1; mm < 64; mm <<= 1) {
                unsigned long long ob = (unsigned long long)__shfl_xor((long long)best, mm);
                best = (ob < best) ? ob : best;
            }
            if (lane == 0) bidx_s[w * RPW + row] = (int)(best & 511ULL);
        }
    }

    // Epilogue: per tile a, lane handles row a*16+l15, chunks l4*8 and 32+l4*8.
    // x recomputed from the fp16 frags (2^-11 rel err; loss-only).
    float lsum = 0.f;
#pragma unroll
    for (int a = 0; a < 2; a++) {
        const int myv = vb + a * 16 + l15;
        const int qb = bidx_s[w * RPW + a * 16 + l15];
        const float* qbase = embed + (size_t)qb * DQ + l4 * 8;
        const float4* qa = (const float4*)qbase;
        const float4* qc = (const float4*)(qbase + 32);
        float4 q0 = qa[0], q1 = qa[1], q2 = qc[0], q3 = qc[1];
        float* obase = out + (size_t)myv * DQ + l4 * 8;
        ((float4*)obase)[0] = q0; ((float4*)obase)[1] = q1;
        ((float4*)(obase + 32))[0] = q2; ((float4*)(obase + 32))[1] = q3;
        if (l4 == 0) out[IDX_OFF + myv] = (float)qb;

        float d;
        d = q0.x - (float)ahA[a][0]; lsum = fmaf(d, d, lsum);
        d = q0.y - (float)ahA[a][1]; lsum = fmaf(d, d, lsum);
        d = q0.z - (float)ahA[a][2]; lsum = fmaf(d, d, lsum);
        d = q0.w - (float)ahA[a][3]; lsum = fmaf(d, d, lsum);
        d = q1.x - (float)ahA[a][4]; lsum = fmaf(d, d, lsum);
        d = q1.y - (float)ahA[a][5]; lsum = fmaf(d, d, lsum);
        d = q1.z - (float)ahA[a][6]; lsum = fmaf(d, d, lsum);
        d = q1.w - (float)ahA[a][7]; lsum = fmaf(d, d, lsum);
        d = q2.x - (float)ahB[a][0]; lsum = fmaf(d, d, lsum);
        d = q2.y - (float)ahB[a][1]; lsum = fmaf(d, d, lsum);
        d = q2.z - (float)ahB[a][2]; lsum = fmaf(d, d, lsum);
        d = q2.w - (float)ahB[a][3]; lsum = fmaf(d, d, lsum);
        d = q3.x - (float)ahB[a][4]; lsum = fmaf(d, d, lsum);
        d = q3.y - (float)ahB[a][5]; lsum = fmaf(d, d, lsum);
        d = q3.z - (float)ahB[a][6]; lsum = fmaf(d, d, lsum);
        d = q3.w - (float)ahB[a][7]; lsum = fmaf(d, d, lsum);
    }

#pragma unroll
    for (int off = 32; off > 0; off >>= 1) lsum += __shfl_down(lsum, off);
    if (lane == 0) red[w] = lsum;
    __syncthreads();
    if (tid == 0) {
        float s = red[0] + red[1];
        atomicAdd(out + LOSS_OFF, s * (2.0f / (float)QOUT_SIZE));
    }
}

extern "C" void kernel_launch(void* const* d_in, const int* in_sizes, int n_in,
                              void* d_out, int out_size, void* d_ws, size_t ws_size,
                              hipStream_t stream) {
    const float* enc = (const float*)d_in[0];
    const float* embed = (const float*)d_in[1];
    float* out = (float*)d_out;
    // ws layout: eh[512*64] u16 | esq[512] f32  (~66 KB)
    unsigned short* eh = (unsigned short*)d_ws;
    float* esq = (float*)(eh + KQ * DQ);

    hipLaunchKernelGGL(vq_init_kernel, dim3(64), dim3(64), 0, stream,
                       embed, eh, esq, out);
    hipLaunchKernelGGL(vq_mfma_kernel, dim3(NBLK), dim3(128), 0, stream,
                       enc, embed, eh, esq, out);
}

// Round 5
// 181.731 us; speedup vs baseline: 1.1227x; 1.1227x over previous
//
#include <hip/hip_runtime.h>
#include <math.h>

// Problem constants (fixed by reference: enc (32,64,64,64) fp32, embed (512,64) fp32)
#define DQ 64
#define KQ 512
#define NVEC 131072
#define QOUT_SIZE (NVEC * DQ)              // 8388608
#define LOSS_OFF QOUT_SIZE
#define IDX_OFF (QOUT_SIZE + 1)

#define RPW 32                             // rows per wave per sweep (2 MFMA A-tiles)
#define WPB 4                              // waves per block (256 threads)
#define VPB (RPW * WPB)                    // 128 rows per sweep per WG
#define SWEEPS 2
#define ROWS_PER_WG (VPB * SWEEPS)         // 256
#define NBLK (NVEC / ROWS_PER_WG)          // 512 blocks -> exactly 2 per CU
// Packed-key scheme: esq stored as |e|^2 + 256 so v = esq - 2*dot > 0 always
// (x_sq ~ chi2(64); 256 is 17 sigma -> impossible). Low 9 mantissa bits carry
// the code index (<=511 ulp ~ 0.002 at d2~60). TIE_THR = fp16-product 5.5
// sigma + pack noise.
#define ESQ_OFF 256.0f
#define TIE_THR 0.09f

typedef __attribute__((ext_vector_type(8))) _Float16 half8;        // 8 f16 = 1 MFMA A/B frag
typedef __attribute__((ext_vector_type(4))) float f32x4;           // MFMA C/D frag

static __device__ __forceinline__ void cvt8h(float4 a, float4 b, half8& h) {
    // RNE f32->f16 (v_cvt_f16_f32 default mode).
    h[0] = (_Float16)a.x; h[1] = (_Float16)a.y; h[2] = (_Float16)a.z; h[3] = (_Float16)a.w;
    h[4] = (_Float16)b.x; h[5] = (_Float16)b.y; h[6] = (_Float16)b.z; h[7] = (_Float16)b.w;
}

// key = distance value with low 9 mantissa bits replaced by the code index.
// Values strictly positive -> IEEE float ordering == bit ordering.
static __device__ __forceinline__ float packk(float v, int code) {
    return __uint_as_float((__float_as_uint(v) & 0xFFFFFE00u) | (unsigned)code);
}

// Init: fp16 codebook in XOR-SWIZZLED layout (chunk c of row k stored at slot
// c ^ (k&7)) so main-kernel ds_read_b128 B-frag reads are conflict-free while
// staging stays a verbatim contiguous copy (R14: conflicts == 0).
// esq = |e|^2 + 256 (see above).
__global__ void vq_init_kernel(const float* __restrict__ embed,
                               unsigned short* __restrict__ eh,
                               float* __restrict__ esq,
                               float* __restrict__ out) {
    const int t = blockIdx.x * 64 + threadIdx.x;   // 0..4095
    if (t == 0) out[LOSS_OFF] = 0.0f;
    const int k = t >> 3;            // codebook row
    const int c = t & 7;             // 16-byte chunk (8 dims)
    const float4* p = (const float4*)(embed + (size_t)k * DQ + c * 8);
    float4 a = p[0], b = p[1];
    half8 h;
    cvt8h(a, b, h);
    const int slot = c ^ (k & 7);    // XOR swizzle
    *(half8*)(eh + (size_t)k * DQ + slot * 8) = h;

    float ps = 0.f;
    ps = fmaf(a.x, a.x, ps); ps = fmaf(a.y, a.y, ps); ps = fmaf(a.z, a.z, ps); ps = fmaf(a.w, a.w, ps);
    ps = fmaf(b.x, b.x, ps); ps = fmaf(b.y, b.y, ps); ps = fmaf(b.z, b.z, ps); ps = fmaf(b.w, b.w, ps);
    ps += __shfl_xor(ps, 1);
    ps += __shfl_xor(ps, 2);
    ps += __shfl_xor(ps, 4);
    if (c == 0) esq[k] = ps + ESQ_OFF;
}

// R17. Post-mortem R16: global-direct B regressed (153 us) — compiler cut
// VGPRs to 96 and serialized the load ping-pong; per-wave latency hit ~34 us.
// Cross-round invariant: residency is ~1-2 WGs/CU in EVERY structure; cross-
// wave stall overlap never materializes. So design for it: (1) 512 WGs x 4
// waves = exactly 2 WGs/CU, each WG owns 256 rows in 2 sweeps -> codebook
// staged to LDS ONCE per WG (fixed cost amortized 2x vs R14, 8x vs R0's
// restage-per-stage). (2) In-wave latency hiding: sweep s+1's 8 enc
// dwordx4 loads issue BEFORE sweep s's k-loop (~5k cyc cover vs ~900 cyc
// HBM). (3) LDS 67 KB pins provable residency at 2 WGs/CU -> VGPR budget
// 512/2 = 256 (R12 rule); demand ~110 -> headroom prevents the R16
// pressure-serialization failure. k-loop = R14's proven LDS pair form
// (packed keys, min3/med3, 2-shuffle merge; conflicts 0).
// R3 lesson kept: VGPR arrays only indexed by fully-unrolled constants.
__global__ __launch_bounds__(256) void vq_mfma_kernel(const float* __restrict__ enc,
                                                      const float* __restrict__ embed,
                                                      const unsigned short* __restrict__ eh,
                                                      const float* __restrict__ esq,
                                                      float* __restrict__ out) {
    __shared__ unsigned short hs[KQ * DQ];     // full fp16 codebook: 64 KB
    __shared__ float esq_s[KQ];                // 2 KB
    __shared__ int bidx_s[VPB];                // 512 B (per-sweep reuse)
    __shared__ int flag_s[VPB];                // 512 B
    __shared__ float red[WPB];

    const int tid = threadIdx.x;               // 0..255
    const int lane = tid & 63;
    const int w = tid >> 6;                    // wave 0..3
    const int l15 = lane & 15;
    const int l4 = lane >> 4;                  // 0..3
    const int base_row = blockIdx.x * ROWS_PER_WG;

    // ---- Issue sweep-0 A loads FIRST (HBM latency overlaps staging). ----
    float4 raw[2][4];
    {
        const int vb0 = base_row + w * RPW;
#pragma unroll
        for (int a = 0; a < 2; a++) {
            const float* b_ = enc + (size_t)(vb0 + a * 16 + l15) * DQ + l4 * 8;
            raw[a][0] = ((const float4*)b_)[0];
            raw[a][1] = ((const float4*)b_)[1];
            raw[a][2] = ((const float4*)(b_ + 32))[0];
            raw[a][3] = ((const float4*)(b_ + 32))[1];
        }
    }

    // ---- One-shot codebook staging: 256 threads x 16 chunks of 16 B. ----
#pragma unroll
    for (int j = 0; j < 16; j++) {
        *(half8*)(hs + j * 2048 + tid * 8) = *(const half8*)(eh + j * 2048 + tid * 8);
    }
    esq_s[tid] = esq[tid];
    esq_s[tid + 256] = esq[tid + 256];
    __syncthreads();                           // the ONLY block-wide barrier before end

    // Swizzled B-frag slot offsets (elements); key = l15&7 (batch*16 == 0 mod 8).
    const int sl0 = (l4 ^ (l15 & 7)) * 8;      // chunk l4     (dims l4*8..+8)
    const int sl1 = sl0 ^ 32;                  // chunk 4+l4   (dims 32+l4*8..+8)
    const unsigned short* hrow = hs + l15 * DQ;    // batch b adds b*1024 elems

    float lsum = 0.f;
    half8 ahA[2], ahB[2];

#pragma unroll 1
    for (int s = 0; s < SWEEPS; s++) {
        const int vb = base_row + s * VPB + w * RPW;

        // Convert this sweep's raw A to fp16 fragments.
#pragma unroll
        for (int a = 0; a < 2; a++) {
            cvt8h(raw[a][0], raw[a][1], ahA[a]);
            cvt8h(raw[a][2], raw[a][3], ahB[a]);
        }
        // Prefetch next sweep's raw A — issued before the k-loop so the
        // ~900-cyc HBM latency hides under ~5k cyc of MFMA+VALU.
        if (s + 1 < SWEEPS) {
            const int vn = base_row + (s + 1) * VPB + w * RPW;
#pragma unroll
            for (int a = 0; a < 2; a++) {
                const float* b_ = enc + (size_t)(vn + a * 16 + l15) * DQ + l4 * 8;
                raw[a][0] = ((const float4*)b_)[0];
                raw[a][1] = ((const float4*)b_)[1];
                raw[a][2] = ((const float4*)(b_ + 32))[0];
                raw[a][3] = ((const float4*)(b_ + 32))[1];
            }
        }

        float m1[8], m2[8];
#pragma unroll
        for (int r = 0; r < 8; r++) { m1[r] = 3.0e38f; m2[r] = 3.0e38f; }

        // k-loop: 16 pairs of 16-code batches. Per pair: 4 ds_read_b128,
        // 8 MFMA, ~56 bookkeeping VALU. Barrier-free.
#pragma unroll 2
        for (int p = 0; p < 16; p++) {
            const int b0 = 2 * p, b1 = 2 * p + 1;
            const half8 B00 = *(const half8*)(hrow + b0 * 1024 + sl0);
            const half8 B01 = *(const half8*)(hrow + b0 * 1024 + sl1);
            const half8 B10 = *(const half8*)(hrow + b1 * 1024 + sl0);
            const half8 B11 = *(const half8*)(hrow + b1 * 1024 + sl1);
            const float ev0 = esq_s[b0 * 16 + l15];
            const float ev1 = esq_s[b1 * 16 + l15];
            const int c0 = b0 * 16 + l15;
#pragma unroll
            for (int a = 0; a < 2; a++) {
                f32x4 acc0 = {0.f, 0.f, 0.f, 0.f};
                f32x4 acc1 = {0.f, 0.f, 0.f, 0.f};
                acc0 = __builtin_amdgcn_mfma_f32_16x16x32_f16(ahA[a], B00, acc0, 0, 0, 0);
                acc0 = __builtin_amdgcn_mfma_f32_16x16x32_f16(ahB[a], B01, acc0, 0, 0, 0);
                acc1 = __builtin_amdgcn_mfma_f32_16x16x32_f16(ahA[a], B10, acc1, 0, 0, 0);
                acc1 = __builtin_amdgcn_mfma_f32_16x16x32_f16(ahB[a], B11, acc1, 0, 0, 0);
#pragma unroll
                for (int r = 0; r < 4; r++) {
                    const int i = a * 4 + r;
                    const float k0 = packk(fmaf(-2.0f, acc0[r], ev0), c0);
                    const float k1 = packk(fmaf(-2.0f, acc1[r], ev1), c0 + 16);
                    const float mo = m1[i];
                    m1[i] = fminf(fminf(mo, k0), k1);                          // v_min3
                    m2[i] = fminf(m2[i], __builtin_amdgcn_fmed3f(mo, k0, k1)); // 2nd-best
                }
            }
        }

        // Cross-lane merge over the 16 cols (xor on lane&15 bits). Keys carry
        // the code index -> only 2 shuffles per r.
#pragma unroll
        for (int m = 1; m <= 8; m <<= 1) {
#pragma unroll
            for (int r = 0; r < 8; r++) {
                const float o1 = __shfl_xor(m1[r], m);
                const float o2 = __shfl_xor(m2[r], m);
                m2[r] = fminf(fminf(m2[r], o2), fmaxf(m1[r], o1));
                m1[r] = fminf(m1[r], o1);
            }
        }

        if (l15 == 0) {
#pragma unroll
            for (int a = 0; a < 2; a++)
#pragma unroll
                for (int r = 0; r < 4; r++) {
                    const int row = a * 16 + l4 * 4 + r;
                    bidx_s[w * RPW + row] = (int)(__float_as_uint(m1[a * 4 + r]) & 511u);
                    flag_s[w * RPW + row] = (m2[a * 4 + r] - m1[a * 4 + r] < TIE_THR) ? 1 : 0;
                }
        }
        // bidx_s/flag_s are per-wave segments -> wave-internal visibility only.

        // Exact fp64 rescan of flagged rows (wave-uniform branch; rare).
        for (int row = 0; row < RPW; row++) {
            if (flag_s[w * RPW + row]) {
                const int v = vb + row;
                const float4* xe = (const float4*)(enc + (size_t)v * DQ);
                unsigned long long best = ~0ULL;
                for (int q = 0; q < 8; q++) {
                    const int c = lane * 8 + q;
                    const float4* ee = (const float4*)(embed + (size_t)c * DQ);
                    double a = 0.0;
                    for (int j = 0; j < 16; j++) {      // global ptrs: runtime j fine
                        float4 xx = xe[j], ez = ee[j];
                        double d0 = (double)xx.x - (double)ez.x; a = fma(d0, d0, a);
                        double d1 = (double)xx.y - (double)ez.y; a = fma(d1, d1, a);
                        double d2 = (double)xx.z - (double)ez.z; a = fma(d2, d2, a);
                        double d3 = (double)xx.w - (double)ez.w; a = fma(d3, d3, a);
                    }
                    unsigned long long pk =
                        (((unsigned long long)__double_as_longlong(a)) & ~511ULL) | (unsigned)c;
                    best = (pk < best) ? pk : best;
                }
#pragma unroll
                for (int mm = 1; mm < 64; mm <<= 1) {
                    unsigned long long ob = (unsigned long long)__shfl_xor((long long)best, mm);
                    best = (ob < best) ? ob : best;
                }
                if (lane == 0) bidx_s[w * RPW + row] = (int)(best & 511ULL);
            }
        }

        // Epilogue: per tile a, lane handles row a*16+l15, chunks l4*8 and
        // 32+l4*8. x recomputed from the fp16 frags (2^-11 rel err; loss-only).
#pragma unroll
        for (int a = 0; a < 2; a++) {
            const int myv = vb + a * 16 + l15;
            const int qb = bidx_s[w * RPW + a * 16 + l15];
            const float* qbase = embed + (size_t)qb * DQ + l4 * 8;
            const float4* qa = (const float4*)qbase;
            const float4* qc = (const float4*)(qbase + 32);
            float4 q0 = qa[0], q1 = qa[1], q2 = qc[0], q3 = qc[1];
            float* obase = out + (size_t)myv * DQ + l4 * 8;
            ((float4*)obase)[0] = q0; ((float4*)obase)[1] = q1;
            ((float4*)(obase + 32))[0] = q2; ((float4*)(obase + 32))[1] = q3;
            if (l4 == 0) out[IDX_OFF + myv] = (float)qb;

            float d;
            d = q0.x - (float)ahA[a][0]; lsum = fmaf(d, d, lsum);
            d = q0.y - (float)ahA[a][1]; lsum = fmaf(d, d, lsum);
            d = q0.z - (float)ahA[a][2]; lsum = fmaf(d, d, lsum);
            d = q0.w - (float)ahA[a][3]; lsum = fmaf(d, d, lsum);
            d = q1.x - (float)ahA[a][4]; lsum = fmaf(d, d, lsum);
            d = q1.y - (float)ahA[a][5]; lsum = fmaf(d, d, lsum);
            d = q1.z - (float)ahA[a][6]; lsum = fmaf(d, d, lsum);
            d = q1.w - (float)ahA[a][7]; lsum = fmaf(d, d, lsum);
            d = q2.x - (float)ahB[a][0]; lsum = fmaf(d, d, lsum);
            d = q2.y - (float)ahB[a][1]; lsum = fmaf(d, d, lsum);
            d = q2.z - (float)ahB[a][2]; lsum = fmaf(d, d, lsum);
            d = q2.w - (float)ahB[a][3]; lsum = fmaf(d, d, lsum);
            d = q3.x - (float)ahB[a][4]; lsum = fmaf(d, d, lsum);
            d = q3.y - (float)ahB[a][5]; lsum = fmaf(d, d, lsum);
            d = q3.z - (float)ahB[a][6]; lsum = fmaf(d, d, lsum);
            d = q3.w - (float)ahB[a][7]; lsum = fmaf(d, d, lsum);
        }
    }

#pragma unroll
    for (int off = 32; off > 0; off >>= 1) lsum += __shfl_down(lsum, off);
    if (lane == 0) red[w] = lsum;
    __syncthreads();
    if (tid == 0) {
        float ssum = (red[0] + red[1]) + (red[2] + red[3]);
        atomicAdd(out + LOSS_OFF, ssum * (2.0f / (float)QOUT_SIZE));
    }
}

extern "C" void kernel_launch(void* const* d_in, const int* in_sizes, int n_in,
                              void* d_out, int out_size, void* d_ws, size_t ws_size,
                              hipStream_t stream) {
    const float* enc = (const float*)d_in[0];
    const float* embed = (const float*)d_in[1];
    float* out = (float*)d_out;
    // ws layout: eh[512*64] u16 | esq[512] f32  (~66 KB)
    unsigned short* eh = (unsigned short*)d_ws;
    float* esq = (float*)(eh + KQ * DQ);

    hipLaunchKernelGGL(vq_init_kernel, dim3(64), dim3(64), 0, stream,
                       embed, eh, esq, out);
    hipLaunchKernelGGL(vq_mfma_kernel, dim3(NBLK), dim3(256), 0, stream,
                       enc, embed, eh, esq, out);
}